// Round 1
// baseline (562.132 us; speedup 1.0000x reference)
//
#include <hip/hip_runtime.h>
#include <math.h>

// Problem constants
#define NA    50      // agents
#define NT    50      // time
#define HIDK  128     // hidden (= K of projection GEMM)
#define NH    32      // heads
#define NC    16      // channels per head
#define NB    32      // batch
#define SAT   2500    // NA*NT  (per-batch rows)
#define NS    2450    // (NA-1)*NT  (softmax length)
#define MTOT  80000   // NB*SAT
#define NOUT  512     // NH*NC

// ============ K_fill: out[b][a][t][:] = bias (ego slice overwritten later) ============
__global__ __launch_bounds__(256) void k_fill(const float* __restrict__ bias,
                                              float* __restrict__ out) {
  size_t i = (size_t)blockIdx.x * 256 + threadIdx.x;   // float4 index; grid sized exactly
  float4 b4 = ((const float4*)bias)[i & 127];          // 512 floats = 128 float4 per row
  ((float4*)out)[i] = b4;
}

// ============ K1: xw[b][h][sat][c] = x[m] . W[n], fused a_src/a_dst epilogue ============
// x viewed as (80000,128) row-major == h input directly (m = (b*50+a)*50+t).
#define TM 64
#define TN 64
#define KC 32
__global__ __launch_bounds__(256) void k1_gemm(
    const float* __restrict__ X,        // (80000,128)
    const float* __restrict__ Wm,       // (512,128)
    const float* __restrict__ att_src,  // (32,16)
    const float* __restrict__ att_dst,  // (32,16)
    float* __restrict__ xw,             // [b][h][2500][16]
    float* __restrict__ asrc,           // [b][h][2500]
    float* __restrict__ adst)           // [b][h][50]
{
  __shared__ float Ast[KC][TM + 4];  // [k][m], stride 68 (16B-aligned rows, conflict-padded)
  __shared__ float Bst[KC][TN + 4];
  const int tid = threadIdx.x;
  const int m0 = blockIdx.y * TM;
  const int n0 = blockIdx.x * TN;
  const int ty = tid >> 4;   // 0..15 -> rows ty*4..+3
  const int tx = tid & 15;   // 0..15 -> cols tx*4..+3

  float acc[4][4] = {};

  const int sr = tid >> 3;   // 0..31 staging row
  const int sc = tid & 7;    // 0..7  staging float4-col

  for (int kc = 0; kc < HIDK; kc += KC) {
    #pragma unroll
    for (int L = 0; L < 2; ++L) {
      int row = sr + L * 32;
      float4 v = *(const float4*)&X[(size_t)(m0 + row) * HIDK + kc + sc * 4];
      Ast[sc*4+0][row] = v.x; Ast[sc*4+1][row] = v.y;
      Ast[sc*4+2][row] = v.z; Ast[sc*4+3][row] = v.w;
      float4 w = *(const float4*)&Wm[(size_t)(n0 + row) * HIDK + kc + sc * 4];
      Bst[sc*4+0][row] = w.x; Bst[sc*4+1][row] = w.y;
      Bst[sc*4+2][row] = w.z; Bst[sc*4+3][row] = w.w;
    }
    __syncthreads();
    #pragma unroll
    for (int k = 0; k < KC; ++k) {
      float4 a4 = *(const float4*)&Ast[k][ty * 4];
      float4 b4 = *(const float4*)&Bst[k][tx * 4];
      float a[4] = {a4.x, a4.y, a4.z, a4.w};
      float b[4] = {b4.x, b4.y, b4.z, b4.w};
      #pragma unroll
      for (int i = 0; i < 4; ++i)
        #pragma unroll
        for (int j = 0; j < 4; ++j)
          acc[i][j] = fmaf(a[i], b[j], acc[i][j]);
    }
    __syncthreads();
  }

  // Epilogue: store xw (transposed layout) + fused a_src/a_dst head-dots.
  const int n = n0 + tx * 4;
  const int hh = n >> 4;          // head
  const int c0 = n & 15;          // channel base (0,4,8,12)
  float ws0[4], wd0[4];
  #pragma unroll
  for (int j = 0; j < 4; ++j) {
    ws0[j] = att_src[hh * NC + c0 + j];
    wd0[j] = att_dst[hh * NC + c0 + j];
  }
  #pragma unroll
  for (int i = 0; i < 4; ++i) {
    int m = m0 + ty * 4 + i;
    int bb = m / SAT;
    int sat = m - bb * SAT;
    size_t rowbase = ((size_t)(bb * NH + hh) * SAT + sat);
    float4 st = {acc[i][0], acc[i][1], acc[i][2], acc[i][3]};
    *(float4*)&xw[(rowbase << 4) + c0] = st;
    float ps = acc[i][0]*ws0[0] + acc[i][1]*ws0[1] + acc[i][2]*ws0[2] + acc[i][3]*ws0[3];
    float pd = acc[i][0]*wd0[0] + acc[i][1]*wd0[1] + acc[i][2]*wd0[2] + acc[i][3]*wd0[3];
    ps += __shfl_xor(ps, 1); ps += __shfl_xor(ps, 2);
    pd += __shfl_xor(pd, 1); pd += __shfl_xor(pd, 2);
    if ((tx & 3) == 0) {
      asrc[rowbase] = ps;
      if (sat < NT) adst[(bb * NH + hh) * NT + sat] = pd;
    }
  }
}

// ============ K3: per (b,h) softmax + weighted sum over S=2450 ============
// max logit per t' is analytic: leaky monotonic => m[t'] = leaky(max_s asrc + adst[t'])
// => single pass, e <= 1 always.
__global__ __launch_bounds__(256) void k3_attn(
    const float* __restrict__ xw, const float* __restrict__ asrc,
    const float* __restrict__ adst, const float* __restrict__ bias,
    float* __restrict__ out)
{
  const int hh = blockIdx.x;
  const int b  = blockIdx.y;
  const int tid = threadIdx.x;

  __shared__ float sA[NS];
  __shared__ float sD[56], sM[56];
  __shared__ float sV[126][16];
  __shared__ float oBuf[56][16];
  __shared__ float zBuf[56];
  __shared__ float redLds[4];
  __shared__ float sMaxA;

  const size_t base = (size_t)b * NH + hh;
  const float* asrcR = asrc + base * SAT + NT;   // skip a=0 rows
  for (int i = tid; i < NS; i += 256) sA[i] = asrcR[i];
  for (int i = tid; i < 56; i += 256) sD[i] = (i < NT) ? adst[base * NT + i] : 0.f;
  for (int i = tid; i < 56 * 16; i += 256) ((float*)oBuf)[i] = 0.f;
  if (tid < 56) zBuf[tid] = 0.f;
  __syncthreads();

  float mx = -1e30f;
  for (int i = tid; i < NS; i += 256) mx = fmaxf(mx, sA[i]);
  #pragma unroll
  for (int off = 32; off; off >>= 1) mx = fmaxf(mx, __shfl_xor(mx, off));
  if ((tid & 63) == 0) redLds[tid >> 6] = mx;
  __syncthreads();
  if (tid == 0)
    sMaxA = fmaxf(fmaxf(redLds[0], redLds[1]), fmaxf(redLds[2], redLds[3]));
  __syncthreads();
  const float maxA = sMaxA;
  if (tid < 56) {
    float x = maxA + sD[tid];
    sM[tid] = (x >= 0.f) ? x : 0.2f * x;
  }
  __syncthreads();

  // roles: 14 slots (7 t-tiles x 2 c-halves) x 18 s-stripes = 252 active threads
  const int slot = tid % 14;
  const int g    = tid / 14;
  const bool active = (g < 18);
  const int tt = slot % 7;       // t' = tt*8 .. +7
  const int ct = slot / 7;       // c  = ct*8 .. +7
  float dreg[8], mreg[8];
  #pragma unroll
  for (int r = 0; r < 8; ++r) { dreg[r] = sD[tt*8 + r]; mreg[r] = sM[tt*8 + r]; }

  float accR[8][8] = {};
  float zacc[8] = {};
  const float4* vsrc = (const float4*)(xw + (base * SAT + NT) * NC);

  for (int s0 = 0; s0 < NS; s0 += 126) {
    const int len = min(126, NS - s0);
    __syncthreads();
    for (int i = tid; i < len * 4; i += 256)
      ((float4*)sV)[i] = vsrc[(size_t)s0 * 4 + i];
    __syncthreads();
    if (active) {
      for (int k = 0; k < 7; ++k) {
        int s = g * 7 + k;
        if (s >= len) break;
        float a_s = sA[s0 + s];
        float e[8];
        #pragma unroll
        for (int r = 0; r < 8; ++r) {
          float x = a_s + dreg[r];
          float l = (x >= 0.f) ? x : 0.2f * x;
          e[r] = __expf(l - mreg[r]);
        }
        float4 v0 = ((const float4*)&sV[s][0])[ct * 2];
        float4 v1 = ((const float4*)&sV[s][0])[ct * 2 + 1];
        float v[8] = {v0.x, v0.y, v0.z, v0.w, v1.x, v1.y, v1.z, v1.w};
        #pragma unroll
        for (int r = 0; r < 8; ++r) {
          #pragma unroll
          for (int q = 0; q < 8; ++q)
            accR[r][q] = fmaf(e[r], v[q], accR[r][q]);
          if (ct == 0) zacc[r] += e[r];
        }
      }
    }
  }

  __syncthreads();
  if (active) {
    #pragma unroll
    for (int r = 0; r < 8; ++r) {
      #pragma unroll
      for (int q = 0; q < 8; ++q)
        atomicAdd(&oBuf[tt*8 + r][ct*8 + q], accR[r][q]);
      if (ct == 0) atomicAdd(&zBuf[tt*8 + r], zacc[r]);
    }
  }
  __syncthreads();

  const float* bh = bias + hh * NC;
  for (int i = tid; i < NT * NC; i += 256) {
    int t = i >> 4, c = i & 15;
    float val = oBuf[t][c] / zBuf[t] + bh[c];
    out[((size_t)b * SAT + t) * NOUT + hh * NC + c] = val;  // a = EGO = 0 slice
  }
}

extern "C" void kernel_launch(void* const* d_in, const int* in_sizes, int n_in,
                              void* d_out, int out_size, void* d_ws, size_t ws_size,
                              hipStream_t stream) {
  const float* X       = (const float*)d_in[0];  // h (32,50,50,128)
  const float* Wm      = (const float*)d_in[1];  // W (512,128)
  const float* att_src = (const float*)d_in[2];  // (32,16)
  const float* att_dst = (const float*)d_in[3];  // (32,16)
  const float* bias    = (const float*)d_in[4];  // (512,)
  float* out = (float*)d_out;

  // workspace layout (fp32): xw 40,960,000 | asrc 2,560,000 | adst 51,200  (~174.3 MB)
  float* xw   = (float*)d_ws;
  float* asrc = xw + (size_t)NB * NH * SAT * NC;
  float* adst = asrc + (size_t)NB * NH * SAT;

  // fill output with bias (ego slice overwritten by k3)
  hipLaunchKernelGGL(k_fill, dim3(40000), dim3(256), 0, stream, bias, out);
  // projection GEMM + fused attention-coefficient dots
  hipLaunchKernelGGL(k1_gemm, dim3(8, 1250), dim3(256), 0, stream,
                     X, Wm, att_src, att_dst, xw, asrc, adst);
  // softmax + weighted aggregation into ego slice
  hipLaunchKernelGGL(k3_attn, dim3(NH, NB), dim3(256), 0, stream,
                     xw, asrc, adst, bias, out);
}